// Round 1
// baseline (93.326 us; speedup 1.0000x reference)
//
#include <hip/hip_runtime.h>

#define S_LEN  4096
#define D_DIM  128
#define MQ     64
#define KT     64
#define NBATCH 4

#define QS_STR 136   // 128 + 8 pad (bf16 elems)
#define KS_STR 136
#define VT_STR 72    // 64 + 8 pad
#define PS_STR 72

typedef __bf16 bf16x8 __attribute__((ext_vector_type(8)));
typedef float  f32x4  __attribute__((ext_vector_type(4)));
typedef unsigned short u16x4 __attribute__((ext_vector_type(4)));
typedef unsigned short u16x8 __attribute__((ext_vector_type(8)));

__device__ __forceinline__ unsigned short f2bf(float f) {
  unsigned int u = __builtin_bit_cast(unsigned int, f);
  u += 0x7fffu + ((u >> 16) & 1u);            // round-to-nearest-even
  return (unsigned short)(u >> 16);
}

__device__ __forceinline__ bf16x8 ld8(const unsigned short* p) {
  return __builtin_bit_cast(bf16x8, *(const u16x8*)p);
}

__device__ __forceinline__ f32x4 mfma16(bf16x8 a, bf16x8 b, f32x4 c) {
  return __builtin_amdgcn_mfma_f32_16x16x32_bf16(a, b, c, 0, 0, 0);
}

__global__ __launch_bounds__(256)
void swa_fwd(const float* __restrict__ Qg, const float* __restrict__ Kg,
             const float* __restrict__ Vg, float* __restrict__ Og)
{
  __shared__ __align__(16) unsigned short lds_q[MQ * QS_STR];
  __shared__ __align__(16) unsigned short lds_k[KT * KS_STR];
  __shared__ __align__(16) unsigned short lds_vt[D_DIM * VT_STR];
  __shared__ __align__(16) unsigned short lds_p[4 * 16 * PS_STR];

  const int tid  = threadIdx.x;
  const int b    = blockIdx.x >> 6;
  const int q0   = (blockIdx.x & 63) * MQ;
  const size_t base = (size_t)b * S_LEN * D_DIM;

  const int lane = tid & 63;
  const int wv   = tid >> 6;
  const int quad = lane >> 4;
  const int l15  = lane & 15;

  // ---- stage Q once; fold log2(e)/sqrt(D) so softmax runs in exp2 domain ----
  {
    const float qsc = 1.4426950408889634f * 0.08838834764831845f;
    const float* gq = Qg + base + (size_t)q0 * D_DIM;
#pragma unroll
    for (int j = 0; j < 8; ++j) {
      const int f = j * 1024 + tid * 4;
      const int row = f >> 7, col = f & 127;
      const f32x4 x = *(const f32x4*)(gq + f);
      u16x4 y;
#pragma unroll
      for (int e = 0; e < 4; ++e) y[e] = f2bf(x[e] * qsc);
      *(u16x4*)&lds_q[row * QS_STR + col] = y;
    }
  }
  __syncthreads();

  // A-fragments: A[m=lane&15][k=quad*8+j]  (verified m120 layout)
  bf16x8 aq[4];
#pragma unroll
  for (int ks = 0; ks < 4; ++ks)
    aq[ks] = ld8(&lds_q[(wv * 16 + l15) * QS_STR + ks * 32 + quad * 8]);

  float mrow[4], lrow[4];
  f32x4 acc[8];
#pragma unroll
  for (int r = 0; r < 4; ++r) { mrow[r] = -3.0e38f; lrow[r] = 0.0f; }
#pragma unroll
  for (int d = 0; d < 8; ++d) acc[d] = (f32x4){0.f, 0.f, 0.f, 0.f};

  for (int t = 0; t < 5; ++t) {
    const int kb = q0 + (t - 2) * KT;
    if (kb < 0 || kb >= S_LEN) continue;   // block-uniform: safe with barriers
    __syncthreads();                        // prior tile's LDS reads done

    // ---- K tile -> LDS (bf16, row=key) ----
    {
      const float* gk = Kg + base + (size_t)kb * D_DIM;
#pragma unroll
      for (int j = 0; j < 8; ++j) {
        const int f = j * 1024 + tid * 4;
        const int row = f >> 7, col = f & 127;
        const f32x4 x = *(const f32x4*)(gk + f);
        u16x4 y;
#pragma unroll
        for (int e = 0; e < 4; ++e) y[e] = f2bf(x[e]);
        *(u16x4*)&lds_k[row * KS_STR + col] = y;
      }
    }
    // ---- V tile -> LDS transposed (row=dim) so PV B-frags are contiguous ----
    {
      const float* gv = Vg + base + (size_t)kb * D_DIM;
      const int d0 = (tid & 31) * 4;
      const int k0 = (tid >> 5) * 8;
      unsigned short vb[4][8];
#pragma unroll
      for (int kk = 0; kk < 8; ++kk) {
        const f32x4 x = *(const f32x4*)(gv + (size_t)(k0 + kk) * D_DIM + d0);
#pragma unroll
        for (int e = 0; e < 4; ++e) vb[e][kk] = f2bf(x[e]);
      }
#pragma unroll
      for (int e = 0; e < 4; ++e) {
        u16x8 y;
#pragma unroll
        for (int kk = 0; kk < 8; ++kk) y[kk] = vb[e][kk];
        *(u16x8*)&lds_vt[(d0 + e) * VT_STR + k0] = y;
      }
    }
    __syncthreads();

    // ---- S = Q K^T : 16 rows x 64 keys per wave ----
    f32x4 sc[4];
#pragma unroll
    for (int cb = 0; cb < 4; ++cb) {
      f32x4 a = (f32x4){0.f, 0.f, 0.f, 0.f};
#pragma unroll
      for (int ks = 0; ks < 4; ++ks) {
        const bf16x8 kf = ld8(&lds_k[(cb * 16 + l15) * KS_STR + ks * 32 + quad * 8]);
        a = mfma16(aq[ks], kf, a);
      }
      sc[cb] = a;
    }

    // ---- band mask: only outer tiles can violate |i-j|<=127 ----
    if (t == 0 || t == 4) {
      const int off = (t - 2) * KT;
#pragma unroll
      for (int cb = 0; cb < 4; ++cb)
#pragma unroll
        for (int r = 0; r < 4; ++r) {
          const int delta = (wv * 16 + quad * 4 + r) - (off + cb * 16 + l15);
          if (delta > 127 || delta < -127) sc[cb][r] = -1.0e30f;
        }
    }

    // ---- online softmax (C layout: col=l15, row=quad*4+r) ----
    float tm[4];
#pragma unroll
    for (int r = 0; r < 4; ++r)
      tm[r] = fmaxf(fmaxf(sc[0][r], sc[1][r]), fmaxf(sc[2][r], sc[3][r]));
#pragma unroll
    for (int r = 0; r < 4; ++r) {
      tm[r] = fmaxf(tm[r], __shfl_xor(tm[r], 1, 64));
      tm[r] = fmaxf(tm[r], __shfl_xor(tm[r], 2, 64));
      tm[r] = fmaxf(tm[r], __shfl_xor(tm[r], 4, 64));
      tm[r] = fmaxf(tm[r], __shfl_xor(tm[r], 8, 64));
    }

    float alpha[4], rs[4];
#pragma unroll
    for (int r = 0; r < 4; ++r) {
      const float mn = fmaxf(mrow[r], tm[r]);
      alpha[r] = exp2f(mrow[r] - mn);
      mrow[r] = mn;
    }
#pragma unroll
    for (int cb = 0; cb < 4; ++cb)
#pragma unroll
      for (int r = 0; r < 4; ++r)
        sc[cb][r] = exp2f(sc[cb][r] - mrow[r]);
#pragma unroll
    for (int r = 0; r < 4; ++r) {
      rs[r] = (sc[0][r] + sc[1][r]) + (sc[2][r] + sc[3][r]);
      rs[r] += __shfl_xor(rs[r], 1, 64);
      rs[r] += __shfl_xor(rs[r], 2, 64);
      rs[r] += __shfl_xor(rs[r], 4, 64);
      rs[r] += __shfl_xor(rs[r], 8, 64);
      lrow[r] = lrow[r] * alpha[r] + rs[r];
    }
#pragma unroll
    for (int d = 0; d < 8; ++d)
#pragma unroll
      for (int r = 0; r < 4; ++r) acc[d][r] *= alpha[r];

    // ---- P: C-layout -> A-layout via per-wave LDS round-trip ----
    unsigned short* pw = &lds_p[wv * 16 * PS_STR];
#pragma unroll
    for (int cb = 0; cb < 4; ++cb)
#pragma unroll
      for (int r = 0; r < 4; ++r)
        pw[(quad * 4 + r) * PS_STR + cb * 16 + l15] = f2bf(sc[cb][r]);

    // ---- O += P V ----
#pragma unroll
    for (int ks2 = 0; ks2 < 2; ++ks2) {
      const bf16x8 pf = ld8(&pw[l15 * PS_STR + ks2 * 32 + quad * 8]);
#pragma unroll
      for (int d = 0; d < 8; ++d) {
        const bf16x8 vf = ld8(&lds_vt[(d * 16 + l15) * VT_STR + ks2 * 32 + quad * 8]);
        acc[d] = mfma16(pf, vf, acc[d]);
      }
    }
  }

  // ---- epilogue: O /= l ----
  float inv[4];
#pragma unroll
  for (int r = 0; r < 4; ++r) inv[r] = 1.0f / lrow[r];
  float* go = Og + base + (size_t)q0 * D_DIM;
#pragma unroll
  for (int d = 0; d < 8; ++d)
#pragma unroll
    for (int r = 0; r < 4; ++r)
      go[(size_t)(wv * 16 + quad * 4 + r) * D_DIM + d * 16 + l15] = acc[d][r] * inv[r];
}

extern "C" void kernel_launch(void* const* d_in, const int* in_sizes, int n_in,
                              void* d_out, int out_size, void* d_ws, size_t ws_size,
                              hipStream_t stream) {
  const float* q = (const float*)d_in[0];
  const float* k = (const float*)d_in[1];
  const float* v = (const float*)d_in[2];
  float* o = (float*)d_out;
  dim3 grid(NBATCH * (S_LEN / MQ));   // 256 blocks: one 64-query tile each
  dim3 block(256);                    // 4 waves; wave w owns rows w*16..w*16+15
  swa_fwd<<<grid, block, 0, stream>>>(q, k, v, o);
}

// Round 2
// 91.595 us; speedup vs baseline: 1.0189x; 1.0189x over previous
//
#include <hip/hip_runtime.h>

#define S_LEN  4096
#define D_DIM  128
#define MQ     64
#define KT     64
#define NBATCH 4

#define QS_STR 136   // 128 + 8 pad (bf16 elems)
#define KS_STR 136
#define VT_STR 72    // 64 + 8 pad
#define PS_STR 72

typedef __bf16 bf16x8 __attribute__((ext_vector_type(8)));
typedef float  f32x4  __attribute__((ext_vector_type(4)));
typedef unsigned short u16x4 __attribute__((ext_vector_type(4)));
typedef unsigned short u16x8 __attribute__((ext_vector_type(8)));

__device__ __forceinline__ unsigned short f2bf(float f) {
  unsigned int u = __builtin_bit_cast(unsigned int, f);
  u += 0x7fffu + ((u >> 16) & 1u);            // round-to-nearest-even
  return (unsigned short)(u >> 16);
}

__device__ __forceinline__ bf16x8 ld8(const unsigned short* p) {
  return __builtin_bit_cast(bf16x8, *(const u16x8*)p);
}

__device__ __forceinline__ f32x4 mfma16(bf16x8 a, bf16x8 b, f32x4 c) {
  return __builtin_amdgcn_mfma_f32_16x16x32_bf16(a, b, c, 0, 0, 0);
}

__global__ __launch_bounds__(256, 1)
void swa_fwd(const float* __restrict__ Qg, const float* __restrict__ Kg,
             const float* __restrict__ Vg, float* __restrict__ Og)
{
  __shared__ __align__(16) unsigned short lds_q[MQ * QS_STR];
  __shared__ __align__(16) unsigned short lds_k[KT * KS_STR];
  __shared__ __align__(16) unsigned short lds_vt[D_DIM * VT_STR];
  __shared__ __align__(16) unsigned short lds_p[4 * 16 * PS_STR];

  const int tid  = threadIdx.x;
  // XCD swizzle: blockIdx%8 = XCD (round-robin dispatch heuristic); give each
  // XCD a contiguous run of 32 q-tiles so the shared K/V band fits its 4MB L2.
  const int g    = (blockIdx.x & 7) * 32 + (blockIdx.x >> 3);
  const int b    = g >> 6;
  const int q0   = (g & 63) * MQ;
  const size_t base = (size_t)b * S_LEN * D_DIM;

  const int lane = tid & 63;
  const int wv   = tid >> 6;
  const int quad = lane >> 4;
  const int l15  = lane & 15;

  // valid tile range: kb = q0 + (t-2)*64 in [0, S-64]
  const int t_lo = (q0 >= 128) ? 0 : (2 - (q0 >> 6));
  const int t_hi = (4032 - q0 >= 128) ? 4 : (2 + ((4032 - q0) >> 6));

  const int vd0 = (tid & 31) * 4;     // V-transpose: dims handled
  const int vk0 = (tid >> 5) * 8;     // keys handled

  // ---- issue Q + first K/V tile loads together (one exposed HBM latency) ----
  f32x4 qreg[8], kreg[8], vreg[8];
  {
    const float* gq = Qg + base + (size_t)q0 * D_DIM;
#pragma unroll
    for (int j = 0; j < 8; ++j) qreg[j] = *(const f32x4*)(gq + j * 1024 + tid * 4);
  }
  int kb = q0 + (t_lo - 2) * KT;
  {
    const float* gk = Kg + base + (size_t)kb * D_DIM;
    const float* gv = Vg + base + (size_t)kb * D_DIM;
#pragma unroll
    for (int j = 0; j < 8; ++j) kreg[j] = *(const f32x4*)(gk + j * 1024 + tid * 4);
#pragma unroll
    for (int kk = 0; kk < 8; ++kk)
      vreg[kk] = *(const f32x4*)(gv + (size_t)(vk0 + kk) * D_DIM + vd0);
  }

  // ---- convert + stage Q (fold log2e/sqrt(D): softmax in exp2 domain) ----
  {
    const float qsc = 1.4426950408889634f * 0.08838834764831845f;
#pragma unroll
    for (int j = 0; j < 8; ++j) {
      const int f = j * 1024 + tid * 4;
      u16x4 y;
#pragma unroll
      for (int e = 0; e < 4; ++e) y[e] = f2bf(qreg[j][e] * qsc);
      *(u16x4*)&lds_q[(f >> 7) * QS_STR + (f & 127)] = y;
    }
  }
  // ---- convert + stage first K/V tile ----
  {
#pragma unroll
    for (int j = 0; j < 8; ++j) {
      const int f = j * 1024 + tid * 4;
      u16x4 y;
#pragma unroll
      for (int e = 0; e < 4; ++e) y[e] = f2bf(kreg[j][e]);
      *(u16x4*)&lds_k[(f >> 7) * KS_STR + (f & 127)] = y;
    }
#pragma unroll
    for (int e = 0; e < 4; ++e) {
      u16x8 y;
#pragma unroll
      for (int kk = 0; kk < 8; ++kk) y[kk] = f2bf(vreg[kk][e]);
      *(u16x8*)&lds_vt[(vd0 + e) * VT_STR + vk0] = y;
    }
  }
  __syncthreads();

  // A-fragments: A[m=lane&15][k=quad*8+j]  (verified m120 layout)
  bf16x8 aq[4];
#pragma unroll
  for (int ks = 0; ks < 4; ++ks)
    aq[ks] = ld8(&lds_q[(wv * 16 + l15) * QS_STR + ks * 32 + quad * 8]);

  float mrow[4], lrow[4];
  f32x4 acc[8];
#pragma unroll
  for (int r = 0; r < 4; ++r) { mrow[r] = -3.0e38f; lrow[r] = 0.0f; }
#pragma unroll
  for (int d = 0; d < 8; ++d) acc[d] = (f32x4){0.f, 0.f, 0.f, 0.f};

  for (int t = t_lo; t <= t_hi; ++t) {
    // ---- prefetch next tile's K/V into registers (in flight during compute) ----
    if (t < t_hi) {
      const float* gk = Kg + base + (size_t)(kb + KT) * D_DIM;
      const float* gv = Vg + base + (size_t)(kb + KT) * D_DIM;
#pragma unroll
      for (int j = 0; j < 8; ++j) kreg[j] = *(const f32x4*)(gk + j * 1024 + tid * 4);
#pragma unroll
      for (int kk = 0; kk < 8; ++kk)
        vreg[kk] = *(const f32x4*)(gv + (size_t)(vk0 + kk) * D_DIM + vd0);
    }

    // ---- S = Q K^T : skip provably fully-masked 16x16 blocks in outer tiles ----
    int cbLo = 0, cbHi = 3;
    if (t == 0) cbLo = wv;       // off=-128: only cb >= wv intersect the band
    if (t == 4) cbHi = wv;       // off=+128: only cb <= wv intersect the band
    f32x4 sc[4];
#pragma unroll
    for (int cb = 0; cb < 4; ++cb) {
      if (cb < cbLo || cb > cbHi) {
        sc[cb] = (f32x4){-1.0e30f, -1.0e30f, -1.0e30f, -1.0e30f};
        continue;
      }
      f32x4 a = (f32x4){0.f, 0.f, 0.f, 0.f};
#pragma unroll
      for (int ks = 0; ks < 4; ++ks) {
        const bf16x8 kf = ld8(&lds_k[(cb * 16 + l15) * KS_STR + ks * 32 + quad * 8]);
        a = mfma16(aq[ks], kf, a);
      }
      sc[cb] = a;
    }

    // ---- band mask (outer tiles only; |i-j|<=127) ----
    if (t == 0 || t == 4) {
      const int off = (t - 2) * KT;
#pragma unroll
      for (int cb = 0; cb < 4; ++cb)
#pragma unroll
        for (int r = 0; r < 4; ++r) {
          const int delta = (wv * 16 + quad * 4 + r) - (off + cb * 16 + l15);
          if (delta > 127 || delta < -127) sc[cb][r] = -1.0e30f;
        }
    }

    // ---- online softmax (C layout: col=l15, row=quad*4+r) ----
    float tm[4];
#pragma unroll
    for (int r = 0; r < 4; ++r)
      tm[r] = fmaxf(fmaxf(sc[0][r], sc[1][r]), fmaxf(sc[2][r], sc[3][r]));
#pragma unroll
    for (int r = 0; r < 4; ++r) {
      tm[r] = fmaxf(tm[r], __shfl_xor(tm[r], 1, 64));
      tm[r] = fmaxf(tm[r], __shfl_xor(tm[r], 2, 64));
      tm[r] = fmaxf(tm[r], __shfl_xor(tm[r], 4, 64));
      tm[r] = fmaxf(tm[r], __shfl_xor(tm[r], 8, 64));
    }

    float alpha[4], rs[4];
#pragma unroll
    for (int r = 0; r < 4; ++r) {
      const float mn = fmaxf(mrow[r], tm[r]);
      alpha[r] = exp2f(mrow[r] - mn);
      mrow[r] = mn;
    }
#pragma unroll
    for (int cb = 0; cb < 4; ++cb)
#pragma unroll
      for (int r = 0; r < 4; ++r)
        sc[cb][r] = exp2f(sc[cb][r] - mrow[r]);
#pragma unroll
    for (int r = 0; r < 4; ++r) {
      rs[r] = (sc[0][r] + sc[1][r]) + (sc[2][r] + sc[3][r]);
      rs[r] += __shfl_xor(rs[r], 1, 64);
      rs[r] += __shfl_xor(rs[r], 2, 64);
      rs[r] += __shfl_xor(rs[r], 4, 64);
      rs[r] += __shfl_xor(rs[r], 8, 64);
      lrow[r] = lrow[r] * alpha[r] + rs[r];
    }
#pragma unroll
    for (int d = 0; d < 8; ++d)
#pragma unroll
      for (int r = 0; r < 4; ++r) acc[d][r] *= alpha[r];

    // ---- P: C-layout -> A-layout via per-wave LDS round-trip ----
    unsigned short* pw = &lds_p[wv * 16 * PS_STR];
#pragma unroll
    for (int cb = 0; cb < 4; ++cb)
#pragma unroll
      for (int r = 0; r < 4; ++r)
        pw[(quad * 4 + r) * PS_STR + cb * 16 + l15] = f2bf(sc[cb][r]);

    // ---- O += P V ----
#pragma unroll
    for (int ks2 = 0; ks2 < 2; ++ks2) {
      const bf16x8 pf = ld8(&pw[l15 * PS_STR + ks2 * 32 + quad * 8]);
#pragma unroll
      for (int d = 0; d < 8; ++d) {
        const bf16x8 vf = ld8(&lds_vt[(d * 16 + l15) * VT_STR + ks2 * 32 + quad * 8]);
        acc[d] = mfma16(pf, vf, acc[d]);
      }
    }

    __syncthreads();   // all waves done reading lds_k / lds_vt
    if (t < t_hi) {
      // ---- convert + write prefetched K/V to LDS ----
#pragma unroll
      for (int j = 0; j < 8; ++j) {
        const int f = j * 1024 + tid * 4;
        u16x4 y;
#pragma unroll
        for (int e = 0; e < 4; ++e) y[e] = f2bf(kreg[j][e]);
        *(u16x4*)&lds_k[(f >> 7) * KS_STR + (f & 127)] = y;
      }
#pragma unroll
      for (int e = 0; e < 4; ++e) {
        u16x8 y;
#pragma unroll
        for (int kk = 0; kk < 8; ++kk) y[kk] = f2bf(vreg[kk][e]);
        *(u16x8*)&lds_vt[(vd0 + e) * VT_STR + vk0] = y;
      }
    }
    __syncthreads();
    kb += KT;
  }

  // ---- epilogue: O /= l ----
  float inv[4];
#pragma unroll
  for (int r = 0; r < 4; ++r) inv[r] = 1.0f / lrow[r];
  float* go = Og + base + (size_t)q0 * D_DIM;
#pragma unroll
  for (int d = 0; d < 8; ++d)
#pragma unroll
    for (int r = 0; r < 4; ++r)
      go[(size_t)(wv * 16 + quad * 4 + r) * D_DIM + d * 16 + l15] = acc[d][r] * inv[r];
}

extern "C" void kernel_launch(void* const* d_in, const int* in_sizes, int n_in,
                              void* d_out, int out_size, void* d_ws, size_t ws_size,
                              hipStream_t stream) {
  const float* q = (const float*)d_in[0];
  const float* k = (const float*)d_in[1];
  const float* v = (const float*)d_in[2];
  float* o = (float*)d_out;
  dim3 grid(NBATCH * (S_LEN / MQ));   // 256 blocks: one 64-query tile each
  dim3 block(256);                    // 4 waves; wave w owns rows w*16..w*16+15
  swa_fwd<<<grid, block, 0, stream>>>(q, k, v, o);
}